// Round 5
// baseline (576.720 us; speedup 1.0000x reference)
//
#include <hip/hip_runtime.h>

#define HID 128
#define MASKV -1000000000.0f
#define INV_TAU 2.0f
#define NB_SHIFT 9          // bucket = dst >> 9 (512 nodes/bucket)
#define ECHUNK 4096

using short8 = __attribute__((ext_vector_type(8))) short;
using f32x4  = __attribute__((ext_vector_type(4))) float;

// ---------- bf16 helpers ----------
__device__ inline ushort f2bf(float f) {
  unsigned u = __float_as_uint(f);
  return (ushort)((u + 0x7FFFu + ((u >> 16) & 1u)) >> 16);
}
__device__ inline float bflo(unsigned u) { return __uint_as_float(u << 16); }
__device__ inline float bfhi(unsigned u) { return __uint_as_float(u & 0xFFFF0000u); }

// ---------- argmax-key helpers ----------
__device__ inline unsigned ordered_bits(float f) {
  unsigned u = __float_as_uint(f);
  return (u & 0x80000000u) ? ~u : (u | 0x80000000u);
}
__device__ inline int key_idx(unsigned long long k) {
  return (int)(0xFFFFFFFFu - (unsigned)(k & 0xFFFFFFFFull));
}

// ---------- weight transpose-convert ----------
__global__ __launch_bounds__(256) void cvt_w(const float* __restrict__ W1, const float* __restrict__ W2,
                                             const float* __restrict__ W3, ushort* __restrict__ Wt) {
  const float* W = (blockIdx.y == 0) ? W1 : (blockIdx.y == 1) ? W2 : W3;
  ushort* o = Wt + (size_t)blockIdx.y * 128 * 128;
  int idx = blockIdx.x * 256 + threadIdx.x;
  int c = idx >> 7, k = idx & 127;
  o[idx] = f2bf(W[k * 128 + c]);
}

// ---------- degree histogram ----------
__global__ __launch_bounds__(256) void deg_hist(const int* __restrict__ ei, int* __restrict__ cnt, int E) {
  int e = blockIdx.x * 256 + threadIdx.x;
  if (e < E) atomicAdd(&cnt[ei[E + e]], 1);
}
__global__ __launch_bounds__(256) void dinv_fin(const int* __restrict__ cnt, float* __restrict__ dinv, int n) {
  int i = blockIdx.x * 256 + threadIdx.x;
  if (i < n) dinv[i] = rsqrtf((float)cnt[i] + 1.0f);
}

// ---------- exclusive scan over node counts ----------
__global__ __launch_bounds__(256) void scan_block(const int* __restrict__ cnt, int* __restrict__ pre,
                                                  int* __restrict__ bsums, int n) {
  __shared__ int sh[256];
  int t = threadIdx.x;
  int base = blockIdx.x * 1024 + t * 4;
  int v0 = 0, v1 = 0, v2 = 0, v3 = 0;
  if (base + 0 < n) v0 = cnt[base + 0];
  if (base + 1 < n) v1 = cnt[base + 1];
  if (base + 2 < n) v2 = cnt[base + 2];
  if (base + 3 < n) v3 = cnt[base + 3];
  int tsum = v0 + v1 + v2 + v3;
  sh[t] = tsum;
  __syncthreads();
  for (int d = 1; d < 256; d <<= 1) {
    int x = (t >= d) ? sh[t - d] : 0;
    __syncthreads();
    sh[t] += x;
    __syncthreads();
  }
  int excl = sh[t] - tsum;
  if (base + 0 < n) pre[base + 0] = excl;
  if (base + 1 < n) pre[base + 1] = excl + v0;
  if (base + 2 < n) pre[base + 2] = excl + v0 + v1;
  if (base + 3 < n) pre[base + 3] = excl + v0 + v1 + v2;
  if (t == 255) bsums[blockIdx.x] = sh[255];
}
__global__ __launch_bounds__(1024) void scan_tops(int* __restrict__ bsums, int nb) {
  __shared__ int sh[1024];
  int t = threadIdx.x;
  int v = (t < nb) ? bsums[t] : 0;
  sh[t] = v;
  __syncthreads();
  for (int d = 1; d < 1024; d <<= 1) {
    int x = (t >= d) ? sh[t - d] : 0;
    __syncthreads();
    sh[t] += x;
    __syncthreads();
  }
  if (t < nb) bsums[t] = sh[t] - v;
}
__global__ __launch_bounds__(256) void scan_add(int* __restrict__ pre, const int* __restrict__ bsums, int n) {
  int i = blockIdx.x * 256 + threadIdx.x;
  if (i < n) pre[i] += bsums[i >> 10];
}

// ---------- bucket cursor init: bucketCursor[b] = rows[b<<NB_SHIFT] ----------
__global__ __launch_bounds__(256) void init_cursors(const int* __restrict__ rows, int* __restrict__ bcur, int nb) {
  int b = blockIdx.x * 256 + threadIdx.x;
  if (b < nb) bcur[b] = rows[b << NB_SHIFT];
}

// ---------- pass C: bucket edges with block-private contiguous ranges ----------
__global__ __launch_bounds__(256) void edge_bucket(const int* __restrict__ ei, int E, int nb,
                                                   int* __restrict__ bcur, int2* __restrict__ staged) {
  __shared__ int ssrc[ECHUNK];
  __shared__ int sdst[ECHUNK];
  __shared__ int hist[256];
  __shared__ int cur[256];
  int t = threadIdx.x;
  int e0 = blockIdx.x * ECHUNK;
  int cnt = min(ECHUNK, E - e0);
  if (t < nb) hist[t] = 0;
  __syncthreads();
  for (int i = t; i < cnt; i += 256) {
    ssrc[i] = ei[e0 + i];
    int d = ei[E + e0 + i];
    sdst[i] = d;
    atomicAdd(&hist[d >> NB_SHIFT], 1);
  }
  __syncthreads();
  if (t < nb) cur[t] = atomicAdd(&bcur[t], hist[t]);
  __syncthreads();
  for (int i = t; i < cnt; i += 256) {
    int d = sdst[i];
    int pos = atomicAdd(&cur[d >> NB_SHIFT], 1);
    staged[pos] = make_int2(ssrc[i], d);
  }
}

// ---------- pass D: per-bucket CSR fill (LDS cursors, L2-local writes) ----------
__global__ __launch_bounds__(256) void bucket_csr(const int2* __restrict__ staged, const int* __restrict__ rows,
                                                  int* __restrict__ col, int E, int n, int nb) {
  __shared__ int lcur[512];
  __shared__ int lrow[512];
  int b = blockIdx.x;
  int t = threadIdx.x;
  int base = b << NB_SHIFT;
  lcur[t] = 0; lcur[t + 256] = 0;
  lrow[t]       = (base + t < n) ? rows[base + t] : 0;
  lrow[t + 256] = (base + t + 256 < n) ? rows[base + t + 256] : 0;
  __syncthreads();
  int start = rows[base];
  int end = (b + 1 < nb) ? rows[(b + 1) << NB_SHIFT] : E;
  for (int i = start + t; i < end; i += 256) {
    int2 p = staged[i];
    int dl = p.y - base;
    int pos = atomicAdd(&lcur[dl], 1);
    col[lrow[dl] + pos] = p.x;
  }
}

// ---------- MFMA GEMM: hW'(bf16) = (A @ W) * dinv[row]; A bf16 or fp32 ----------
template <int F32IN>
__global__ __launch_bounds__(256) void mfma_gemm(const void* __restrict__ Ain, const ushort* __restrict__ Wt,
                                                 const float* __restrict__ dinv, ushort* __restrict__ hW, int n) {
  int w = threadIdx.x >> 6;
  int l = threadIdx.x & 63;
  int lr = l & 15;
  int lg = l >> 4;
  int r0 = blockIdx.x * 64 + w * 16;
  if (r0 >= n) return;
  int arow = r0 + lr;
  if (arow >= n) arow = n - 1;

  f32x4 acc[8];
#pragma unroll
  for (int ct = 0; ct < 8; ++ct) acc[ct] = (f32x4){0.f, 0.f, 0.f, 0.f};

#pragma unroll
  for (int kk = 0; kk < 4; ++kk) {
    short8 a;
    if (F32IN) {
      const float* Af = (const float*)Ain + (size_t)arow * 128 + kk * 32 + lg * 8;
      float4 f0 = ((const float4*)Af)[0];
      float4 f1 = ((const float4*)Af)[1];
      a[0] = (short)f2bf(f0.x); a[1] = (short)f2bf(f0.y);
      a[2] = (short)f2bf(f0.z); a[3] = (short)f2bf(f0.w);
      a[4] = (short)f2bf(f1.x); a[5] = (short)f2bf(f1.y);
      a[6] = (short)f2bf(f1.z); a[7] = (short)f2bf(f1.w);
    } else {
      a = ((const short8*)((const ushort*)Ain + (size_t)arow * 128))[kk * 4 + lg];
    }
#pragma unroll
    for (int ct = 0; ct < 8; ++ct) {
      short8 bfrag = ((const short8*)(Wt + (size_t)(ct * 16 + lr) * 128))[kk * 4 + lg];
      acc[ct] = __builtin_amdgcn_mfma_f32_16x16x32_bf16(a, bfrag, acc[ct], 0, 0, 0);
    }
  }

#pragma unroll
  for (int r = 0; r < 4; ++r) {
    int row = r0 + lg * 4 + r;
    if (row < n) {
      float dv = dinv[row];
#pragma unroll
      for (int ct = 0; ct < 8; ++ct) {
        hW[(size_t)row * 128 + ct * 16 + lr] = f2bf(acc[ct][r] * dv);
      }
    }
  }
}

// ---------- fused gather: out = relu(dinv[g]*(hW'[g] + sum hW'[src]) + b) ----------
template <int OUTBF>
__global__ __launch_bounds__(256) void gather_k(const int* __restrict__ row_start, const int* __restrict__ cnt,
                                                const int* __restrict__ col, const ushort* __restrict__ hW,
                                                const float* __restrict__ dinv, const float* __restrict__ bias,
                                                void* __restrict__ outp, int n) {
  int g = (blockIdx.x * 256 + threadIdx.x) >> 5;
  if (g >= n) return;
  int lane = threadIdx.x & 31;
  uint2 hv = *(const uint2*)(hW + (size_t)g * 128 + lane * 4);
  float a0 = bflo(hv.x), a1 = bfhi(hv.x), a2 = bflo(hv.y), a3 = bfhi(hv.y);
  int jb = row_start[g];
  int je = jb + cnt[g];
  int j = jb;
  for (; j + 2 <= je; j += 2) {
    int s0 = col[j];
    int s1 = col[j + 1];
    uint2 v0 = *(const uint2*)(hW + (size_t)s0 * 128 + lane * 4);
    uint2 v1 = *(const uint2*)(hW + (size_t)s1 * 128 + lane * 4);
    a0 += bflo(v0.x); a1 += bfhi(v0.x);
    a2 += bflo(v0.y); a3 += bfhi(v0.y);
    a0 += bflo(v1.x); a1 += bfhi(v1.x);
    a2 += bflo(v1.y); a3 += bfhi(v1.y);
  }
  if (j < je) {
    int s0 = col[j];
    uint2 v0 = *(const uint2*)(hW + (size_t)s0 * 128 + lane * 4);
    a0 += bflo(v0.x); a1 += bfhi(v0.x);
    a2 += bflo(v0.y); a3 += bfhi(v0.y);
  }
  float din = dinv[g];
  float4 bb = ((const float4*)bias)[lane];
  a0 = fmaxf(fmaf(a0, din, bb.x), 0.f);
  a1 = fmaxf(fmaf(a1, din, bb.y), 0.f);
  a2 = fmaxf(fmaf(a2, din, bb.z), 0.f);
  a3 = fmaxf(fmaf(a3, din, bb.w), 0.f);
  if (OUTBF) {
    ushort4 o = {f2bf(a0), f2bf(a1), f2bf(a2), f2bf(a3)};
    *(ushort4*)((ushort*)outp + (size_t)g * 128 + lane * 4) = o;
  } else {
    ((float4*)outp)[(size_t)g * 32 + lane] = make_float4(a0, a1, a2, a3);
  }
}

// ---------- pooling ----------
#define POOL_ROWS 64
__global__ __launch_bounds__(128) void pool_kernel(const float* __restrict__ gcn, float* __restrict__ psum,
                                                   float* __restrict__ pmax, int nrows) {
  int k = threadIdx.x;
  int r0 = blockIdx.x * POOL_ROWS;
  int r1 = min(r0 + POOL_ROWS, nrows);
  float s = 0.f, m = 0.f;
  for (int r = r0; r < r1; ++r) {
    float v = gcn[(size_t)r * HID + k];
    s += v;
    m = fmaxf(m, v);
  }
  atomicAdd(&psum[k], s);
  atomicMax((unsigned*)&pmax[k], __float_as_uint(m));
}
__global__ __launch_bounds__(128) void pool_fin(const float* __restrict__ psum, const float* __restrict__ pmax,
                                                float* __restrict__ pool, float invn) {
  int k = threadIdx.x;
  pool[k] = psum[k] * invn;
  pool[128 + k] = pmax[k];
}

// ---------- fused head: GEMV + mask + gumbel + exp (no-max) + sum + argmax ----------
__global__ __launch_bounds__(256) void head_fused(const float* __restrict__ W, const float* __restrict__ bias,
                                                  const float* __restrict__ g, const float* __restrict__ pool,
                                                  const int* __restrict__ conn, int use_conn,
                                                  float* __restrict__ ebuf, unsigned long long* __restrict__ cell,
                                                  float* __restrict__ sum, int maxn, int n) {
  __shared__ float p[256];
  __shared__ unsigned long long kred[256];
  __shared__ float sred[256];
  int t = threadIdx.x;
  p[t] = pool[t];
  __syncthreads();
  int j = blockIdx.x * 256 + t;
  unsigned long long key = 0ull;
  float ev = 0.f;
  if (j < maxn) {
    float acc = 0.f;
#pragma unroll 8
    for (int k = 0; k < 256; ++k) acc = fmaf(p[k], W[(size_t)k * maxn + j], acc);
    float logit = acc + bias[j];
    if (j >= n) logit = MASKV;
    if (use_conn && conn[j]) logit = MASKV;
    float zv = (logit + g[j]) * INV_TAU;
    ev = expf(zv);                 // z <= ~25: no overflow; masked -> exp(-2e9)=0
    ebuf[j] = ev;
    key = ((unsigned long long)ordered_bits(zv) << 32) | (unsigned long long)(0xFFFFFFFFu - (unsigned)j);
  }
  kred[t] = key;
  sred[t] = ev;
  __syncthreads();
  for (int s = 128; s > 0; s >>= 1) {
    if (t < s) {
      kred[t] = kred[t] > kred[t + s] ? kred[t] : kred[t + s];
      sred[t] += sred[t + s];
    }
    __syncthreads();
  }
  if (t == 0) {
    atomicMax(cell, kred[0]);
    atomicAdd(sum, sred[0]);
  }
}

// ---------- normalize both heads ----------
__global__ __launch_bounds__(256) void norm2(const float* __restrict__ e1, const float* __restrict__ s1,
                                             const float* __restrict__ e2, const float* __restrict__ s2,
                                             float* __restrict__ out, int maxn) {
  int j = blockIdx.x * 256 + threadIdx.x;
  if (j < maxn) {
    out[j] = e1[j] / (*s1);
    out[maxn + j] = e2[j] / (*s2);
  }
}

// ---------- connectivity mask ----------
__global__ __launch_bounds__(256) void conn_kernel(const int* __restrict__ ei, int E,
                                                   const unsigned long long* __restrict__ cell1,
                                                   int* __restrict__ conn) {
  int e = blockIdx.x * 256 + threadIdx.x;
  int i1 = key_idx(*cell1);
  if (e == 0) conn[i1] = 1;
  if (e < E) {
    int s = ei[e], d = ei[E + e];
    if (s == i1 || d == i1) {
      conn[s] = 1;
      conn[d] = 1;
    }
  }
}

// ---------- edge head + stop head ----------
__global__ __launch_bounds__(128) void edge_head(const float* __restrict__ gcn, const float* __restrict__ eW,
                                                 const float* __restrict__ ebias, const float* __restrict__ ge,
                                                 const unsigned long long* __restrict__ c1,
                                                 const unsigned long long* __restrict__ c2,
                                                 float* __restrict__ out_base) {
  __shared__ float red[3 * 128];
  int t = threadIdx.x;
  int i1 = key_idx(*c1);
  int i2 = key_idx(*c2);
  float ea = gcn[(size_t)i1 * HID + t];
  float eb2 = gcn[(size_t)i2 * HID + t];
  float p0 = ea * eW[t * 3 + 0] + eb2 * eW[(128 + t) * 3 + 0];
  float p1 = ea * eW[t * 3 + 1] + eb2 * eW[(128 + t) * 3 + 1];
  float p2 = ea * eW[t * 3 + 2] + eb2 * eW[(128 + t) * 3 + 2];
  red[t] = p0; red[128 + t] = p1; red[256 + t] = p2;
  __syncthreads();
  for (int s = 64; s > 0; s >>= 1) {
    if (t < s) {
      red[t] += red[t + s];
      red[128 + t] += red[128 + t + s];
      red[256 + t] += red[256 + t + s];
    }
    __syncthreads();
  }
  if (t == 0) {
    float z0 = (red[0]   + ebias[0] + ge[0]) * INV_TAU;
    float z1 = (red[128] + ebias[1] + ge[1]) * INV_TAU;
    float z2 = (red[256] + ebias[2] + ge[2]) * INV_TAU;
    float m = fmaxf(z0, fmaxf(z1, z2));
    float e0 = expf(z0 - m), e1 = expf(z1 - m), e2 = expf(z2 - m);
    float inv = 1.f / (e0 + e1 + e2);
    out_base[0] = e0 * inv;
    out_base[1] = e1 * inv;
    out_base[2] = e2 * inv;
    out_base[3] = 1.0f;
  }
}

// ---------- launch ----------
extern "C" void kernel_launch(void* const* d_in, const int* in_sizes, int n_in,
                              void* d_out, int out_size, void* d_ws, size_t ws_size,
                              hipStream_t stream) {
  const float* x  = (const float*)d_in[0];
  const int* ei   = (const int*)d_in[1];
  const float* W1 = (const float*)d_in[2];
  const float* b1 = (const float*)d_in[3];
  const float* W2 = (const float*)d_in[4];
  const float* b2 = (const float*)d_in[5];
  const float* W3 = (const float*)d_in[6];
  const float* b3 = (const float*)d_in[7];
  const float* n1W = (const float*)d_in[8];
  const float* n1b = (const float*)d_in[9];
  const float* n2W = (const float*)d_in[10];
  const float* n2b = (const float*)d_in[11];
  const float* eW  = (const float*)d_in[12];
  const float* eb  = (const float*)d_in[13];
  const float* g1  = (const float*)d_in[16];
  const float* g2  = (const float*)d_in[17];
  const float* ge  = (const float*)d_in[18];

  int n    = in_sizes[0] / HID;
  int E    = in_sizes[1] / 2;
  int maxn = in_sizes[9];
  int nb   = (n + (1 << NB_SHIFT) - 1) >> NB_SHIFT;   // node buckets (<=256)
  float* out = (float*)d_out;

  char* ws = (char*)d_ws;
  size_t o = 0;
  ushort* H1B = (ushort*)(ws + o); o += (size_t)n * HID * 2;   // layer-1 out bf16
  ushort* H2B = (ushort*)(ws + o); o += (size_t)n * HID * 2;   // layer-2 out bf16
  ushort* HW  = (ushort*)(ws + o); o += (size_t)n * HID * 2;   // hW' bf16
  float* GCN  = (float*)(ws + o);  o += (size_t)n * HID * 4;   // layer-3 out fp32
  ushort* WT  = (ushort*)(ws + o); o += (size_t)3 * 128 * 128 * 2;
  float* EB1  = (float*)(ws + o);  o += (size_t)maxn * 4;
  float* EB2  = (float*)(ws + o);  o += (size_t)maxn * 4;
  int* ROWS   = (int*)(ws + o);    o += (size_t)n * 4;
  int* COL    = (int*)(ws + o);    o += (size_t)E * 4;
  int2* STAGED = (int2*)(ws + o);  o += (size_t)E * 8;
  float* DINV = (float*)(ws + o);  o += (size_t)n * 4;
  int* BSUMS  = (int*)(ws + o);    o += 1024 * 4;
  int* BCUR   = (int*)(ws + o);    o += 256 * 4;
  // ---- zeroed region ----
  char* zero_start = ws + o;
  int* CNT    = (int*)(ws + o);    o += (size_t)n * 4;
  int* CONN   = (int*)(ws + o);    o += (size_t)maxn * 4;
  float* PS   = (float*)(ws + o);  o += 128 * 4;
  float* PM   = (float*)(ws + o);  o += 128 * 4;
  unsigned long long* CELLS = (unsigned long long*)(ws + o);
  float* SUM1 = (float*)(ws + o + 16);
  float* SUM2 = (float*)(ws + o + 20);
  o += 64;
  size_t zero_bytes = (size_t)((ws + o) - zero_start);
  float* POOL = (float*)(ws + o);  o += 256 * 4;

  hipMemsetAsync(zero_start, 0, zero_bytes, stream);

  dim3 blk(256);
  int gE = (E + 255) / 256;
  int gN = (n + 255) / 256;
  int gHead = (maxn + 255) / 256;
  int gGemm = (n + 63) / 64;
  int gGather = (int)(((size_t)n * 32 + 255) / 256);
  int nScanBlocks = (n + 1023) / 1024;
  int gEB = (E + ECHUNK - 1) / ECHUNK;

  // weights -> bf16 transposed
  cvt_w<<<dim3(64, 3), blk, 0, stream>>>(W1, W2, W3, WT);

  // degrees + dinv + row offsets
  deg_hist<<<gE, blk, 0, stream>>>(ei, CNT, E);
  dinv_fin<<<gN, blk, 0, stream>>>(CNT, DINV, n);
  scan_block<<<nScanBlocks, blk, 0, stream>>>(CNT, ROWS, BSUMS, n);
  scan_tops<<<1, dim3(1024), 0, stream>>>(BSUMS, nScanBlocks);
  scan_add<<<gN, blk, 0, stream>>>(ROWS, BSUMS, n);

  // locality-preserving CSR build
  init_cursors<<<1, blk, 0, stream>>>(ROWS, BCUR, nb);
  edge_bucket<<<gEB, blk, 0, stream>>>(ei, E, nb, BCUR, STAGED);
  bucket_csr<<<nb, blk, 0, stream>>>(STAGED, ROWS, COL, E, n, nb);

  // layer 1: x (fp32, converted inline) -> H1B
  mfma_gemm<1><<<gGemm, blk, 0, stream>>>(x, WT, DINV, HW, n);
  gather_k<1><<<gGather, blk, 0, stream>>>(ROWS, CNT, COL, HW, DINV, b1, H1B, n);
  // layer 2: H1B -> H2B
  mfma_gemm<0><<<gGemm, blk, 0, stream>>>(H1B, WT + 128 * 128, DINV, HW, n);
  gather_k<1><<<gGather, blk, 0, stream>>>(ROWS, CNT, COL, HW, DINV, b2, H2B, n);
  // layer 3: H2B -> GCN (fp32)
  mfma_gemm<0><<<gGemm, blk, 0, stream>>>(H2B, WT + 2 * 128 * 128, DINV, HW, n);
  gather_k<0><<<gGather, blk, 0, stream>>>(ROWS, CNT, COL, HW, DINV, b3, GCN, n);

  // pool
  pool_kernel<<<(n + POOL_ROWS - 1) / POOL_ROWS, dim3(128), 0, stream>>>(GCN, PS, PM, n);
  pool_fin<<<1, dim3(128), 0, stream>>>(PS, PM, POOL, 1.0f / (float)n);

  // head 1 (exp+sum+argmax fused, no max-subtraction needed)
  head_fused<<<gHead, blk, 0, stream>>>(n1W, n1b, g1, POOL, nullptr, 0, EB1, &CELLS[0], SUM1, maxn, n);

  // conn mask from i1
  conn_kernel<<<gE, blk, 0, stream>>>(ei, E, &CELLS[0], CONN);

  // head 2
  head_fused<<<gHead, blk, 0, stream>>>(n2W, n2b, g2, POOL, CONN, 1, EB2, &CELLS[1], SUM2, maxn, n);

  // normalize both heads
  norm2<<<gHead, blk, 0, stream>>>(EB1, SUM1, EB2, SUM2, out, maxn);

  // edge + stop heads
  edge_head<<<1, dim3(128), 0, stream>>>(GCN, eW, eb, ge, &CELLS[0], &CELLS[1], out + 2 * (size_t)maxn);
}

// Round 6
// 575.898 us; speedup vs baseline: 1.0014x; 1.0014x over previous
//
#include <hip/hip_runtime.h>

#define HID 128
#define MASKV -1000000000.0f
#define INV_TAU 2.0f
#define NB_SHIFT 9          // bucket = dst >> 9 (512 nodes/bucket)
#define ECHUNK 4096

using short8 = __attribute__((ext_vector_type(8))) short;
using f32x4  = __attribute__((ext_vector_type(4))) float;

// ---------- bf16 helpers ----------
__device__ inline ushort f2bf(float f) {
  unsigned u = __float_as_uint(f);
  return (ushort)((u + 0x7FFFu + ((u >> 16) & 1u)) >> 16);
}
__device__ inline float bflo(unsigned u) { return __uint_as_float(u << 16); }
__device__ inline float bfhi(unsigned u) { return __uint_as_float(u & 0xFFFF0000u); }

// ---------- argmax-key helpers ----------
__device__ inline unsigned ordered_bits(float f) {
  unsigned u = __float_as_uint(f);
  return (u & 0x80000000u) ? ~u : (u | 0x80000000u);
}
__device__ inline int key_idx(unsigned long long k) {
  return (int)(0xFFFFFFFFu - (unsigned)(k & 0xFFFFFFFFull));
}

// ---------- weight transpose-convert ----------
__global__ __launch_bounds__(256) void cvt_w(const float* __restrict__ W1, const float* __restrict__ W2,
                                             const float* __restrict__ W3, ushort* __restrict__ Wt) {
  const float* W = (blockIdx.y == 0) ? W1 : (blockIdx.y == 1) ? W2 : W3;
  ushort* o = Wt + (size_t)blockIdx.y * 128 * 128;
  int idx = blockIdx.x * 256 + threadIdx.x;
  int c = idx >> 7, k = idx & 127;
  o[idx] = f2bf(W[k * 128 + c]);
}

// ---------- degree histogram ----------
__global__ __launch_bounds__(256) void deg_hist(const int* __restrict__ ei, int* __restrict__ cnt, int E) {
  int e = blockIdx.x * 256 + threadIdx.x;
  if (e < E) atomicAdd(&cnt[ei[E + e]], 1);
}
__global__ __launch_bounds__(256) void dinv_fin(const int* __restrict__ cnt, float* __restrict__ dinv, int n) {
  int i = blockIdx.x * 256 + threadIdx.x;
  if (i < n) dinv[i] = rsqrtf((float)cnt[i] + 1.0f);
}

// ---------- exclusive scan over node counts ----------
__global__ __launch_bounds__(256) void scan_block(const int* __restrict__ cnt, int* __restrict__ pre,
                                                  int* __restrict__ bsums, int n) {
  __shared__ int sh[256];
  int t = threadIdx.x;
  int base = blockIdx.x * 1024 + t * 4;
  int v0 = 0, v1 = 0, v2 = 0, v3 = 0;
  if (base + 0 < n) v0 = cnt[base + 0];
  if (base + 1 < n) v1 = cnt[base + 1];
  if (base + 2 < n) v2 = cnt[base + 2];
  if (base + 3 < n) v3 = cnt[base + 3];
  int tsum = v0 + v1 + v2 + v3;
  sh[t] = tsum;
  __syncthreads();
  for (int d = 1; d < 256; d <<= 1) {
    int x = (t >= d) ? sh[t - d] : 0;
    __syncthreads();
    sh[t] += x;
    __syncthreads();
  }
  int excl = sh[t] - tsum;
  if (base + 0 < n) pre[base + 0] = excl;
  if (base + 1 < n) pre[base + 1] = excl + v0;
  if (base + 2 < n) pre[base + 2] = excl + v0 + v1;
  if (base + 3 < n) pre[base + 3] = excl + v0 + v1 + v2;
  if (t == 255) bsums[blockIdx.x] = sh[255];
}
__global__ __launch_bounds__(1024) void scan_tops(int* __restrict__ bsums, int nb) {
  __shared__ int sh[1024];
  int t = threadIdx.x;
  int v = (t < nb) ? bsums[t] : 0;
  sh[t] = v;
  __syncthreads();
  for (int d = 1; d < 1024; d <<= 1) {
    int x = (t >= d) ? sh[t - d] : 0;
    __syncthreads();
    sh[t] += x;
    __syncthreads();
  }
  if (t < nb) bsums[t] = sh[t] - v;
}
__global__ __launch_bounds__(256) void scan_add(int* __restrict__ pre, const int* __restrict__ bsums, int n) {
  int i = blockIdx.x * 256 + threadIdx.x;
  if (i < n) pre[i] += bsums[i >> 10];
}

// ---------- bucket cursor init: bucketCursor[b] = rows[b<<NB_SHIFT] ----------
__global__ __launch_bounds__(256) void init_cursors(const int* __restrict__ rows, int* __restrict__ bcur, int nb) {
  int b = blockIdx.x * 256 + threadIdx.x;
  if (b < nb) bcur[b] = rows[b << NB_SHIFT];
}

// ---------- pass C: bucket edges with block-private contiguous ranges ----------
__global__ __launch_bounds__(256) void edge_bucket(const int* __restrict__ ei, int E, int nb,
                                                   int* __restrict__ bcur, int2* __restrict__ staged) {
  __shared__ int ssrc[ECHUNK];
  __shared__ int sdst[ECHUNK];
  __shared__ int hist[256];
  __shared__ int cur[256];
  int t = threadIdx.x;
  int e0 = blockIdx.x * ECHUNK;
  int cnt = min(ECHUNK, E - e0);
  if (t < nb) hist[t] = 0;
  __syncthreads();
  for (int i = t; i < cnt; i += 256) {
    ssrc[i] = ei[e0 + i];
    int d = ei[E + e0 + i];
    sdst[i] = d;
    atomicAdd(&hist[d >> NB_SHIFT], 1);
  }
  __syncthreads();
  if (t < nb) cur[t] = atomicAdd(&bcur[t], hist[t]);
  __syncthreads();
  for (int i = t; i < cnt; i += 256) {
    int d = sdst[i];
    int pos = atomicAdd(&cur[d >> NB_SHIFT], 1);
    staged[pos] = make_int2(ssrc[i], d);
  }
}

// ---------- pass D: per-bucket CSR fill (LDS cursors, L2-local writes) ----------
__global__ __launch_bounds__(256) void bucket_csr(const int2* __restrict__ staged, const int* __restrict__ rows,
                                                  int* __restrict__ col, int E, int n, int nb) {
  __shared__ int lcur[512];
  __shared__ int lrow[512];
  int b = blockIdx.x;
  int t = threadIdx.x;
  int base = b << NB_SHIFT;
  lcur[t] = 0; lcur[t + 256] = 0;
  lrow[t]       = (base + t < n) ? rows[base + t] : 0;
  lrow[t + 256] = (base + t + 256 < n) ? rows[base + t + 256] : 0;
  __syncthreads();
  int start = rows[base];
  int end = (b + 1 < nb) ? rows[(b + 1) << NB_SHIFT] : E;
  for (int i = start + t; i < end; i += 256) {
    int2 p = staged[i];
    int dl = p.y - base;
    int pos = atomicAdd(&lcur[dl], 1);
    col[lrow[dl] + pos] = p.x;
  }
}

// ---------- MFMA GEMM: hW'(bf16) = (A @ W) * dinv[row]; A bf16 or fp32 ----------
template <int F32IN>
__global__ __launch_bounds__(256) void mfma_gemm(const void* __restrict__ Ain, const ushort* __restrict__ Wt,
                                                 const float* __restrict__ dinv, ushort* __restrict__ hW, int n) {
  int w = threadIdx.x >> 6;
  int l = threadIdx.x & 63;
  int lr = l & 15;
  int lg = l >> 4;
  int r0 = blockIdx.x * 64 + w * 16;
  if (r0 >= n) return;
  int arow = r0 + lr;
  if (arow >= n) arow = n - 1;

  f32x4 acc[8];
#pragma unroll
  for (int ct = 0; ct < 8; ++ct) acc[ct] = (f32x4){0.f, 0.f, 0.f, 0.f};

#pragma unroll
  for (int kk = 0; kk < 4; ++kk) {
    short8 a;
    if (F32IN) {
      const float* Af = (const float*)Ain + (size_t)arow * 128 + kk * 32 + lg * 8;
      float4 f0 = ((const float4*)Af)[0];
      float4 f1 = ((const float4*)Af)[1];
      a[0] = (short)f2bf(f0.x); a[1] = (short)f2bf(f0.y);
      a[2] = (short)f2bf(f0.z); a[3] = (short)f2bf(f0.w);
      a[4] = (short)f2bf(f1.x); a[5] = (short)f2bf(f1.y);
      a[6] = (short)f2bf(f1.z); a[7] = (short)f2bf(f1.w);
    } else {
      a = ((const short8*)((const ushort*)Ain + (size_t)arow * 128))[kk * 4 + lg];
    }
#pragma unroll
    for (int ct = 0; ct < 8; ++ct) {
      short8 bfrag = ((const short8*)(Wt + (size_t)(ct * 16 + lr) * 128))[kk * 4 + lg];
      acc[ct] = __builtin_amdgcn_mfma_f32_16x16x32_bf16(a, bfrag, acc[ct], 0, 0, 0);
    }
  }

#pragma unroll
  for (int r = 0; r < 4; ++r) {
    int row = r0 + lg * 4 + r;
    if (row < n) {
      float dv = dinv[row];
#pragma unroll
      for (int ct = 0; ct < 8; ++ct) {
        hW[(size_t)row * 128 + ct * 16 + lr] = f2bf(acc[ct][r] * dv);
      }
    }
  }
}

// ---------- fused gather: out = relu(dinv[g]*(hW'[g] + sum hW'[src]) + b) ----------
template <int OUTBF>
__global__ __launch_bounds__(256) void gather_k(const int* __restrict__ row_start, const int* __restrict__ cnt,
                                                const int* __restrict__ col, const ushort* __restrict__ hW,
                                                const float* __restrict__ dinv, const float* __restrict__ bias,
                                                void* __restrict__ outp, int n) {
  int g = (blockIdx.x * 256 + threadIdx.x) >> 5;
  if (g >= n) return;
  int lane = threadIdx.x & 31;
  uint2 hv = *(const uint2*)(hW + (size_t)g * 128 + lane * 4);
  float a0 = bflo(hv.x), a1 = bfhi(hv.x), a2 = bflo(hv.y), a3 = bfhi(hv.y);
  int jb = row_start[g];
  int je = jb + cnt[g];
  int j = jb;
  for (; j + 2 <= je; j += 2) {
    int s0 = col[j];
    int s1 = col[j + 1];
    uint2 v0 = *(const uint2*)(hW + (size_t)s0 * 128 + lane * 4);
    uint2 v1 = *(const uint2*)(hW + (size_t)s1 * 128 + lane * 4);
    a0 += bflo(v0.x); a1 += bfhi(v0.x);
    a2 += bflo(v0.y); a3 += bfhi(v0.y);
    a0 += bflo(v1.x); a1 += bfhi(v1.x);
    a2 += bflo(v1.y); a3 += bfhi(v1.y);
  }
  if (j < je) {
    int s0 = col[j];
    uint2 v0 = *(const uint2*)(hW + (size_t)s0 * 128 + lane * 4);
    a0 += bflo(v0.x); a1 += bfhi(v0.x);
    a2 += bflo(v0.y); a3 += bfhi(v0.y);
  }
  float din = dinv[g];
  float4 bb = ((const float4*)bias)[lane];
  a0 = fmaxf(fmaf(a0, din, bb.x), 0.f);
  a1 = fmaxf(fmaf(a1, din, bb.y), 0.f);
  a2 = fmaxf(fmaf(a2, din, bb.z), 0.f);
  a3 = fmaxf(fmaf(a3, din, bb.w), 0.f);
  if (OUTBF) {
    ushort4 o = {f2bf(a0), f2bf(a1), f2bf(a2), f2bf(a3)};
    *(ushort4*)((ushort*)outp + (size_t)g * 128 + lane * 4) = o;
  } else {
    ((float4*)outp)[(size_t)g * 32 + lane] = make_float4(a0, a1, a2, a3);
  }
}

// ---------- pooling ----------
#define POOL_ROWS 64
__global__ __launch_bounds__(128) void pool_kernel(const float* __restrict__ gcn, float* __restrict__ psum,
                                                   float* __restrict__ pmax, int nrows) {
  int k = threadIdx.x;
  int r0 = blockIdx.x * POOL_ROWS;
  int r1 = min(r0 + POOL_ROWS, nrows);
  float s = 0.f, m = 0.f;
  for (int r = r0; r < r1; ++r) {
    float v = gcn[(size_t)r * HID + k];
    s += v;
    m = fmaxf(m, v);
  }
  atomicAdd(&psum[k], s);
  atomicMax((unsigned*)&pmax[k], __float_as_uint(m));
}
__global__ __launch_bounds__(128) void pool_fin(const float* __restrict__ psum, const float* __restrict__ pmax,
                                                float* __restrict__ pool, float invn) {
  int k = threadIdx.x;
  pool[k] = psum[k] * invn;
  pool[128 + k] = pmax[k];
}

// ---------- fused head: GEMV + mask + gumbel + exp (no-max) + sum + argmax ----------
__global__ __launch_bounds__(256) void head_fused(const float* __restrict__ W, const float* __restrict__ bias,
                                                  const float* __restrict__ g, const float* __restrict__ pool,
                                                  const int* __restrict__ conn, int use_conn,
                                                  float* __restrict__ ebuf, unsigned long long* __restrict__ cell,
                                                  float* __restrict__ sum, int maxn, int n) {
  __shared__ float p[256];
  __shared__ unsigned long long kred[256];
  __shared__ float sred[256];
  int t = threadIdx.x;
  p[t] = pool[t];
  __syncthreads();
  int j = blockIdx.x * 256 + t;
  unsigned long long key = 0ull;
  float ev = 0.f;
  if (j < maxn) {
    float acc = 0.f;
#pragma unroll 8
    for (int k = 0; k < 256; ++k) acc = fmaf(p[k], W[(size_t)k * maxn + j], acc);
    float logit = acc + bias[j];
    if (j >= n) logit = MASKV;
    if (use_conn && conn[j]) logit = MASKV;
    float zv = (logit + g[j]) * INV_TAU;
    ev = expf(zv);                 // z <= ~25: no overflow; masked -> exp(-2e9)=0
    ebuf[j] = ev;
    key = ((unsigned long long)ordered_bits(zv) << 32) | (unsigned long long)(0xFFFFFFFFu - (unsigned)j);
  }
  kred[t] = key;
  sred[t] = ev;
  __syncthreads();
  for (int s = 128; s > 0; s >>= 1) {
    if (t < s) {
      kred[t] = kred[t] > kred[t + s] ? kred[t] : kred[t + s];
      sred[t] += sred[t + s];
    }
    __syncthreads();
  }
  if (t == 0) {
    atomicMax(cell, kred[0]);
    atomicAdd(sum, sred[0]);
  }
}

// ---------- normalize both heads ----------
__global__ __launch_bounds__(256) void norm2(const float* __restrict__ e1, const float* __restrict__ s1,
                                             const float* __restrict__ e2, const float* __restrict__ s2,
                                             float* __restrict__ out, int maxn) {
  int j = blockIdx.x * 256 + threadIdx.x;
  if (j < maxn) {
    out[j] = e1[j] / (*s1);
    out[maxn + j] = e2[j] / (*s2);
  }
}

// ---------- connectivity mask ----------
__global__ __launch_bounds__(256) void conn_kernel(const int* __restrict__ ei, int E,
                                                   const unsigned long long* __restrict__ cell1,
                                                   int* __restrict__ conn) {
  int e = blockIdx.x * 256 + threadIdx.x;
  int i1 = key_idx(*cell1);
  if (e == 0) conn[i1] = 1;
  if (e < E) {
    int s = ei[e], d = ei[E + e];
    if (s == i1 || d == i1) {
      conn[s] = 1;
      conn[d] = 1;
    }
  }
}

// ---------- edge head + stop head ----------
__global__ __launch_bounds__(128) void edge_head(const float* __restrict__ gcn, const float* __restrict__ eW,
                                                 const float* __restrict__ ebias, const float* __restrict__ ge,
                                                 const unsigned long long* __restrict__ c1,
                                                 const unsigned long long* __restrict__ c2,
                                                 float* __restrict__ out_base) {
  __shared__ float red[3 * 128];
  int t = threadIdx.x;
  int i1 = key_idx(*c1);
  int i2 = key_idx(*c2);
  float ea = gcn[(size_t)i1 * HID + t];
  float eb2 = gcn[(size_t)i2 * HID + t];
  float p0 = ea * eW[t * 3 + 0] + eb2 * eW[(128 + t) * 3 + 0];
  float p1 = ea * eW[t * 3 + 1] + eb2 * eW[(128 + t) * 3 + 1];
  float p2 = ea * eW[t * 3 + 2] + eb2 * eW[(128 + t) * 3 + 2];
  red[t] = p0; red[128 + t] = p1; red[256 + t] = p2;
  __syncthreads();
  for (int s = 64; s > 0; s >>= 1) {
    if (t < s) {
      red[t] += red[t + s];
      red[128 + t] += red[128 + t + s];
      red[256 + t] += red[256 + t + s];
    }
    __syncthreads();
  }
  if (t == 0) {
    float z0 = (red[0]   + ebias[0] + ge[0]) * INV_TAU;
    float z1 = (red[128] + ebias[1] + ge[1]) * INV_TAU;
    float z2 = (red[256] + ebias[2] + ge[2]) * INV_TAU;
    float m = fmaxf(z0, fmaxf(z1, z2));
    float e0 = expf(z0 - m), e1 = expf(z1 - m), e2 = expf(z2 - m);
    float inv = 1.f / (e0 + e1 + e2);
    out_base[0] = e0 * inv;
    out_base[1] = e1 * inv;
    out_base[2] = e2 * inv;
    out_base[3] = 1.0f;
  }
}

// ---------- launch ----------
extern "C" void kernel_launch(void* const* d_in, const int* in_sizes, int n_in,
                              void* d_out, int out_size, void* d_ws, size_t ws_size,
                              hipStream_t stream) {
  const float* x  = (const float*)d_in[0];
  const int* ei   = (const int*)d_in[1];
  const float* W1 = (const float*)d_in[2];
  const float* b1 = (const float*)d_in[3];
  const float* W2 = (const float*)d_in[4];
  const float* b2 = (const float*)d_in[5];
  const float* W3 = (const float*)d_in[6];
  const float* b3 = (const float*)d_in[7];
  const float* n1W = (const float*)d_in[8];
  const float* n1b = (const float*)d_in[9];
  const float* n2W = (const float*)d_in[10];
  const float* n2b = (const float*)d_in[11];
  const float* eW  = (const float*)d_in[12];
  const float* eb  = (const float*)d_in[13];
  const float* g1  = (const float*)d_in[16];
  const float* g2  = (const float*)d_in[17];
  const float* ge  = (const float*)d_in[18];

  int n    = in_sizes[0] / HID;
  int E    = in_sizes[1] / 2;
  int maxn = in_sizes[9];
  int nb   = (n + (1 << NB_SHIFT) - 1) >> NB_SHIFT;   // node buckets (<=256)
  float* out = (float*)d_out;

  char* ws = (char*)d_ws;
  size_t o = 0;
  ushort* H1B = (ushort*)(ws + o); o += (size_t)n * HID * 2;   // layer-1 out bf16
  ushort* H2B = (ushort*)(ws + o); o += (size_t)n * HID * 2;   // layer-2 out bf16
  ushort* HW  = (ushort*)(ws + o); o += (size_t)n * HID * 2;   // hW' bf16
  float* GCN  = (float*)(ws + o);  o += (size_t)n * HID * 4;   // layer-3 out fp32
  ushort* WT  = (ushort*)(ws + o); o += (size_t)3 * 128 * 128 * 2;
  float* EB1  = (float*)(ws + o);  o += (size_t)maxn * 4;
  float* EB2  = (float*)(ws + o);  o += (size_t)maxn * 4;
  int* ROWS   = (int*)(ws + o);    o += (size_t)n * 4;
  int* COL    = (int*)(ws + o);    o += (size_t)E * 4;
  int2* STAGED = (int2*)(ws + o);  o += (size_t)E * 8;
  float* DINV = (float*)(ws + o);  o += (size_t)n * 4;
  int* BSUMS  = (int*)(ws + o);    o += 1024 * 4;
  int* BCUR   = (int*)(ws + o);    o += 256 * 4;
  // ---- zeroed region ----
  char* zero_start = ws + o;
  int* CNT    = (int*)(ws + o);    o += (size_t)n * 4;
  int* CONN   = (int*)(ws + o);    o += (size_t)maxn * 4;
  float* PS   = (float*)(ws + o);  o += 128 * 4;
  float* PM   = (float*)(ws + o);  o += 128 * 4;
  unsigned long long* CELLS = (unsigned long long*)(ws + o);
  float* SUM1 = (float*)(ws + o + 16);
  float* SUM2 = (float*)(ws + o + 20);
  o += 64;
  size_t zero_bytes = (size_t)((ws + o) - zero_start);
  float* POOL = (float*)(ws + o);  o += 256 * 4;

  hipMemsetAsync(zero_start, 0, zero_bytes, stream);

  dim3 blk(256);
  int gE = (E + 255) / 256;
  int gN = (n + 255) / 256;
  int gHead = (maxn + 255) / 256;
  int gGemm = (n + 63) / 64;
  int gGather = (int)(((size_t)n * 32 + 255) / 256);
  int nScanBlocks = (n + 1023) / 1024;
  int gEB = (E + ECHUNK - 1) / ECHUNK;

  // weights -> bf16 transposed
  cvt_w<<<dim3(64, 3), blk, 0, stream>>>(W1, W2, W3, WT);

  // degrees + dinv + row offsets
  deg_hist<<<gE, blk, 0, stream>>>(ei, CNT, E);
  dinv_fin<<<gN, blk, 0, stream>>>(CNT, DINV, n);
  scan_block<<<nScanBlocks, blk, 0, stream>>>(CNT, ROWS, BSUMS, n);
  scan_tops<<<1, dim3(1024), 0, stream>>>(BSUMS, nScanBlocks);
  scan_add<<<gN, blk, 0, stream>>>(ROWS, BSUMS, n);

  // locality-preserving CSR build
  init_cursors<<<1, blk, 0, stream>>>(ROWS, BCUR, nb);
  edge_bucket<<<gEB, blk, 0, stream>>>(ei, E, nb, BCUR, STAGED);
  bucket_csr<<<nb, blk, 0, stream>>>(STAGED, ROWS, COL, E, n, nb);

  // layer 1: x (fp32, converted inline) -> H1B
  mfma_gemm<1><<<gGemm, blk, 0, stream>>>(x, WT, DINV, HW, n);
  gather_k<1><<<gGather, blk, 0, stream>>>(ROWS, CNT, COL, HW, DINV, b1, H1B, n);
  // layer 2: H1B -> H2B
  mfma_gemm<0><<<gGemm, blk, 0, stream>>>(H1B, WT + 128 * 128, DINV, HW, n);
  gather_k<1><<<gGather, blk, 0, stream>>>(ROWS, CNT, COL, HW, DINV, b2, H2B, n);
  // layer 3: H2B -> GCN (fp32)
  mfma_gemm<0><<<gGemm, blk, 0, stream>>>(H2B, WT + 2 * 128 * 128, DINV, HW, n);
  gather_k<0><<<gGather, blk, 0, stream>>>(ROWS, CNT, COL, HW, DINV, b3, GCN, n);

  // pool
  pool_kernel<<<(n + POOL_ROWS - 1) / POOL_ROWS, dim3(128), 0, stream>>>(GCN, PS, PM, n);
  pool_fin<<<1, dim3(128), 0, stream>>>(PS, PM, POOL, 1.0f / (float)n);

  // head 1 (exp+sum+argmax fused, no max-subtraction needed)
  head_fused<<<gHead, blk, 0, stream>>>(n1W, n1b, g1, POOL, nullptr, 0, EB1, &CELLS[0], SUM1, maxn, n);

  // conn mask from i1
  conn_kernel<<<gE, blk, 0, stream>>>(ei, E, &CELLS[0], CONN);

  // head 2
  head_fused<<<gHead, blk, 0, stream>>>(n2W, n2b, g2, POOL, CONN, 1, EB2, &CELLS[1], SUM2, maxn, n);

  // normalize both heads
  norm2<<<gHead, blk, 0, stream>>>(EB1, SUM1, EB2, SUM2, out, maxn);

  // edge + stop heads
  edge_head<<<1, dim3(128), 0, stream>>>(GCN, eW, eb, ge, &CELLS[0], &CELLS[1], out + 2 * (size_t)maxn);
}

// Round 7
// 574.878 us; speedup vs baseline: 1.0032x; 1.0018x over previous
//
#include <hip/hip_runtime.h>

#define HID 128
#define MASKV -1000000000.0f
#define INV_TAU 2.0f
#define NB_SHIFT 9          // bucket = dst >> 9 (512 nodes/bucket)
#define ECHUNK 4096

using short8 = __attribute__((ext_vector_type(8))) short;
using f32x4  = __attribute__((ext_vector_type(4))) float;

// ---------- bf16 helpers ----------
__device__ inline ushort f2bf(float f) {
  unsigned u = __float_as_uint(f);
  return (ushort)((u + 0x7FFFu + ((u >> 16) & 1u)) >> 16);
}
__device__ inline float bflo(unsigned u) { return __uint_as_float(u << 16); }
__device__ inline float bfhi(unsigned u) { return __uint_as_float(u & 0xFFFF0000u); }

// ---------- argmax-key helpers ----------
__device__ inline unsigned ordered_bits(float f) {
  unsigned u = __float_as_uint(f);
  return (u & 0x80000000u) ? ~u : (u | 0x80000000u);
}
__device__ inline int key_idx(unsigned long long k) {
  return (int)(0xFFFFFFFFu - (unsigned)(k & 0xFFFFFFFFull));
}

// ---------- weight transpose-convert ----------
__global__ __launch_bounds__(256) void cvt_w(const float* __restrict__ W1, const float* __restrict__ W2,
                                             const float* __restrict__ W3, ushort* __restrict__ Wt) {
  const float* W = (blockIdx.y == 0) ? W1 : (blockIdx.y == 1) ? W2 : W3;
  ushort* o = Wt + (size_t)blockIdx.y * 128 * 128;
  int idx = blockIdx.x * 256 + threadIdx.x;
  int c = idx >> 7, k = idx & 127;
  o[idx] = f2bf(W[k * 128 + c]);
}

// ---------- degree histogram ----------
__global__ __launch_bounds__(256) void deg_hist(const int* __restrict__ ei, int* __restrict__ cnt, int E) {
  int e = blockIdx.x * 256 + threadIdx.x;
  if (e < E) atomicAdd(&cnt[ei[E + e]], 1);
}
__global__ __launch_bounds__(256) void dinv_fin(const int* __restrict__ cnt, float* __restrict__ dinv, int n) {
  int i = blockIdx.x * 256 + threadIdx.x;
  if (i < n) dinv[i] = rsqrtf((float)cnt[i] + 1.0f);
}

// ---------- exclusive scan over node counts ----------
__global__ __launch_bounds__(256) void scan_block(const int* __restrict__ cnt, int* __restrict__ pre,
                                                  int* __restrict__ bsums, int n) {
  __shared__ int sh[256];
  int t = threadIdx.x;
  int base = blockIdx.x * 1024 + t * 4;
  int v0 = 0, v1 = 0, v2 = 0, v3 = 0;
  if (base + 0 < n) v0 = cnt[base + 0];
  if (base + 1 < n) v1 = cnt[base + 1];
  if (base + 2 < n) v2 = cnt[base + 2];
  if (base + 3 < n) v3 = cnt[base + 3];
  int tsum = v0 + v1 + v2 + v3;
  sh[t] = tsum;
  __syncthreads();
  for (int d = 1; d < 256; d <<= 1) {
    int x = (t >= d) ? sh[t - d] : 0;
    __syncthreads();
    sh[t] += x;
    __syncthreads();
  }
  int excl = sh[t] - tsum;
  if (base + 0 < n) pre[base + 0] = excl;
  if (base + 1 < n) pre[base + 1] = excl + v0;
  if (base + 2 < n) pre[base + 2] = excl + v0 + v1;
  if (base + 3 < n) pre[base + 3] = excl + v0 + v1 + v2;
  if (t == 255) bsums[blockIdx.x] = sh[255];
}
__global__ __launch_bounds__(1024) void scan_tops(int* __restrict__ bsums, int nb) {
  __shared__ int sh[1024];
  int t = threadIdx.x;
  int v = (t < nb) ? bsums[t] : 0;
  sh[t] = v;
  __syncthreads();
  for (int d = 1; d < 1024; d <<= 1) {
    int x = (t >= d) ? sh[t - d] : 0;
    __syncthreads();
    sh[t] += x;
    __syncthreads();
  }
  if (t < nb) bsums[t] = sh[t] - v;
}
__global__ __launch_bounds__(256) void scan_add(int* __restrict__ pre, const int* __restrict__ bsums, int n) {
  int i = blockIdx.x * 256 + threadIdx.x;
  if (i < n) pre[i] += bsums[i >> 10];
}

// ---------- bucket cursor init: bucketCursor[b] = rows[b<<NB_SHIFT] ----------
__global__ __launch_bounds__(256) void init_cursors(const int* __restrict__ rows, int* __restrict__ bcur, int nb) {
  int b = blockIdx.x * 256 + threadIdx.x;
  if (b < nb) bcur[b] = rows[b << NB_SHIFT];
}

// ---------- pass C: bucket edges with block-private contiguous ranges ----------
__global__ __launch_bounds__(256) void edge_bucket(const int* __restrict__ ei, int E, int nb,
                                                   int* __restrict__ bcur, int2* __restrict__ staged) {
  __shared__ int ssrc[ECHUNK];
  __shared__ int sdst[ECHUNK];
  __shared__ int hist[256];
  __shared__ int cur[256];
  int t = threadIdx.x;
  int e0 = blockIdx.x * ECHUNK;
  int cnt = min(ECHUNK, E - e0);
  if (t < nb) hist[t] = 0;
  __syncthreads();
  for (int i = t; i < cnt; i += 256) {
    ssrc[i] = ei[e0 + i];
    int d = ei[E + e0 + i];
    sdst[i] = d;
    atomicAdd(&hist[d >> NB_SHIFT], 1);
  }
  __syncthreads();
  if (t < nb) cur[t] = atomicAdd(&bcur[t], hist[t]);
  __syncthreads();
  for (int i = t; i < cnt; i += 256) {
    int d = sdst[i];
    int pos = atomicAdd(&cur[d >> NB_SHIFT], 1);
    staged[pos] = make_int2(ssrc[i], d);
  }
}

// ---------- pass D: per-bucket CSR fill (LDS cursors, L2-local writes) ----------
__global__ __launch_bounds__(256) void bucket_csr(const int2* __restrict__ staged, const int* __restrict__ rows,
                                                  int* __restrict__ col, int E, int n, int nb) {
  __shared__ int lcur[512];
  __shared__ int lrow[512];
  int b = blockIdx.x;
  int t = threadIdx.x;
  int base = b << NB_SHIFT;
  lcur[t] = 0; lcur[t + 256] = 0;
  lrow[t]       = (base + t < n) ? rows[base + t] : 0;
  lrow[t + 256] = (base + t + 256 < n) ? rows[base + t + 256] : 0;
  __syncthreads();
  int start = rows[base];
  int end = (b + 1 < nb) ? rows[(b + 1) << NB_SHIFT] : E;
  for (int i = start + t; i < end; i += 256) {
    int2 p = staged[i];
    int dl = p.y - base;
    int pos = atomicAdd(&lcur[dl], 1);
    col[lrow[dl] + pos] = p.x;
  }
}

// ---------- MFMA GEMM: hW'(bf16) = (A @ W) * dinv[row]; A bf16 or fp32 ----------
template <int F32IN>
__global__ __launch_bounds__(256) void mfma_gemm(const void* __restrict__ Ain, const ushort* __restrict__ Wt,
                                                 const float* __restrict__ dinv, ushort* __restrict__ hW, int n) {
  int w = threadIdx.x >> 6;
  int l = threadIdx.x & 63;
  int lr = l & 15;
  int lg = l >> 4;
  int r0 = blockIdx.x * 64 + w * 16;
  if (r0 >= n) return;
  int arow = r0 + lr;
  if (arow >= n) arow = n - 1;

  f32x4 acc[8];
#pragma unroll
  for (int ct = 0; ct < 8; ++ct) acc[ct] = (f32x4){0.f, 0.f, 0.f, 0.f};

#pragma unroll
  for (int kk = 0; kk < 4; ++kk) {
    short8 a;
    if (F32IN) {
      const float* Af = (const float*)Ain + (size_t)arow * 128 + kk * 32 + lg * 8;
      float4 f0 = ((const float4*)Af)[0];
      float4 f1 = ((const float4*)Af)[1];
      a[0] = (short)f2bf(f0.x); a[1] = (short)f2bf(f0.y);
      a[2] = (short)f2bf(f0.z); a[3] = (short)f2bf(f0.w);
      a[4] = (short)f2bf(f1.x); a[5] = (short)f2bf(f1.y);
      a[6] = (short)f2bf(f1.z); a[7] = (short)f2bf(f1.w);
    } else {
      a = ((const short8*)((const ushort*)Ain + (size_t)arow * 128))[kk * 4 + lg];
    }
#pragma unroll
    for (int ct = 0; ct < 8; ++ct) {
      short8 bfrag = ((const short8*)(Wt + (size_t)(ct * 16 + lr) * 128))[kk * 4 + lg];
      acc[ct] = __builtin_amdgcn_mfma_f32_16x16x32_bf16(a, bfrag, acc[ct], 0, 0, 0);
    }
  }

#pragma unroll
  for (int r = 0; r < 4; ++r) {
    int row = r0 + lg * 4 + r;
    if (row < n) {
      float dv = dinv[row];
#pragma unroll
      for (int ct = 0; ct < 8; ++ct) {
        hW[(size_t)row * 128 + ct * 16 + lr] = f2bf(acc[ct][r] * dv);
      }
    }
  }
}

// ---------- fused gather: out = relu(dinv[g]*(hW'[g] + sum hW'[src]) + b) ----------
template <int OUTBF>
__global__ __launch_bounds__(256) void gather_k(const int* __restrict__ row_start, const int* __restrict__ cnt,
                                                const int* __restrict__ col, const ushort* __restrict__ hW,
                                                const float* __restrict__ dinv, const float* __restrict__ bias,
                                                void* __restrict__ outp, int n) {
  int g = (blockIdx.x * 256 + threadIdx.x) >> 5;
  if (g >= n) return;
  int lane = threadIdx.x & 31;
  uint2 hv = *(const uint2*)(hW + (size_t)g * 128 + lane * 4);
  float a0 = bflo(hv.x), a1 = bfhi(hv.x), a2 = bflo(hv.y), a3 = bfhi(hv.y);
  int jb = row_start[g];
  int je = jb + cnt[g];
  int j = jb;
  for (; j + 2 <= je; j += 2) {
    int s0 = col[j];
    int s1 = col[j + 1];
    uint2 v0 = *(const uint2*)(hW + (size_t)s0 * 128 + lane * 4);
    uint2 v1 = *(const uint2*)(hW + (size_t)s1 * 128 + lane * 4);
    a0 += bflo(v0.x); a1 += bfhi(v0.x);
    a2 += bflo(v0.y); a3 += bfhi(v0.y);
    a0 += bflo(v1.x); a1 += bfhi(v1.x);
    a2 += bflo(v1.y); a3 += bfhi(v1.y);
  }
  if (j < je) {
    int s0 = col[j];
    uint2 v0 = *(const uint2*)(hW + (size_t)s0 * 128 + lane * 4);
    a0 += bflo(v0.x); a1 += bfhi(v0.x);
    a2 += bflo(v0.y); a3 += bfhi(v0.y);
  }
  float din = dinv[g];
  float4 bb = ((const float4*)bias)[lane];
  a0 = fmaxf(fmaf(a0, din, bb.x), 0.f);
  a1 = fmaxf(fmaf(a1, din, bb.y), 0.f);
  a2 = fmaxf(fmaf(a2, din, bb.z), 0.f);
  a3 = fmaxf(fmaf(a3, din, bb.w), 0.f);
  if (OUTBF) {
    ushort4 o = {f2bf(a0), f2bf(a1), f2bf(a2), f2bf(a3)};
    *(ushort4*)((ushort*)outp + (size_t)g * 128 + lane * 4) = o;
  } else {
    ((float4*)outp)[(size_t)g * 32 + lane] = make_float4(a0, a1, a2, a3);
  }
}

// ---------- pooling ----------
#define POOL_ROWS 64
__global__ __launch_bounds__(128) void pool_kernel(const float* __restrict__ gcn, float* __restrict__ psum,
                                                   float* __restrict__ pmax, int nrows) {
  int k = threadIdx.x;
  int r0 = blockIdx.x * POOL_ROWS;
  int r1 = min(r0 + POOL_ROWS, nrows);
  float s = 0.f, m = 0.f;
  for (int r = r0; r < r1; ++r) {
    float v = gcn[(size_t)r * HID + k];
    s += v;
    m = fmaxf(m, v);
  }
  atomicAdd(&psum[k], s);
  atomicMax((unsigned*)&pmax[k], __float_as_uint(m));
}
__global__ __launch_bounds__(128) void pool_fin(const float* __restrict__ psum, const float* __restrict__ pmax,
                                                float* __restrict__ pool, float invn) {
  int k = threadIdx.x;
  pool[k] = psum[k] * invn;
  pool[128 + k] = pmax[k];
}

// ---------- fused head: GEMV + mask + gumbel + exp (no-max) + sum + argmax ----------
__global__ __launch_bounds__(256) void head_fused(const float* __restrict__ W, const float* __restrict__ bias,
                                                  const float* __restrict__ g, const float* __restrict__ pool,
                                                  const int* __restrict__ conn, int use_conn,
                                                  float* __restrict__ ebuf, unsigned long long* __restrict__ cell,
                                                  float* __restrict__ sum, int maxn, int n) {
  __shared__ float p[256];
  __shared__ unsigned long long kred[256];
  __shared__ float sred[256];
  int t = threadIdx.x;
  p[t] = pool[t];
  __syncthreads();
  int j = blockIdx.x * 256 + t;
  unsigned long long key = 0ull;
  float ev = 0.f;
  if (j < maxn) {
    float acc = 0.f;
#pragma unroll 8
    for (int k = 0; k < 256; ++k) acc = fmaf(p[k], W[(size_t)k * maxn + j], acc);
    float logit = acc + bias[j];
    if (j >= n) logit = MASKV;
    if (use_conn && conn[j]) logit = MASKV;
    float zv = (logit + g[j]) * INV_TAU;
    ev = expf(zv);                 // z <= ~25: no overflow; masked -> exp(-2e9)=0
    ebuf[j] = ev;
    key = ((unsigned long long)ordered_bits(zv) << 32) | (unsigned long long)(0xFFFFFFFFu - (unsigned)j);
  }
  kred[t] = key;
  sred[t] = ev;
  __syncthreads();
  for (int s = 128; s > 0; s >>= 1) {
    if (t < s) {
      kred[t] = kred[t] > kred[t + s] ? kred[t] : kred[t + s];
      sred[t] += sred[t + s];
    }
    __syncthreads();
  }
  if (t == 0) {
    atomicMax(cell, kred[0]);
    atomicAdd(sum, sred[0]);
  }
}

// ---------- normalize both heads ----------
__global__ __launch_bounds__(256) void norm2(const float* __restrict__ e1, const float* __restrict__ s1,
                                             const float* __restrict__ e2, const float* __restrict__ s2,
                                             float* __restrict__ out, int maxn) {
  int j = blockIdx.x * 256 + threadIdx.x;
  if (j < maxn) {
    out[j] = e1[j] / (*s1);
    out[maxn + j] = e2[j] / (*s2);
  }
}

// ---------- connectivity mask ----------
__global__ __launch_bounds__(256) void conn_kernel(const int* __restrict__ ei, int E,
                                                   const unsigned long long* __restrict__ cell1,
                                                   int* __restrict__ conn) {
  int e = blockIdx.x * 256 + threadIdx.x;
  int i1 = key_idx(*cell1);
  if (e == 0) conn[i1] = 1;
  if (e < E) {
    int s = ei[e], d = ei[E + e];
    if (s == i1 || d == i1) {
      conn[s] = 1;
      conn[d] = 1;
    }
  }
}

// ---------- edge head + stop head ----------
__global__ __launch_bounds__(128) void edge_head(const float* __restrict__ gcn, const float* __restrict__ eW,
                                                 const float* __restrict__ ebias, const float* __restrict__ ge,
                                                 const unsigned long long* __restrict__ c1,
                                                 const unsigned long long* __restrict__ c2,
                                                 float* __restrict__ out_base) {
  __shared__ float red[3 * 128];
  int t = threadIdx.x;
  int i1 = key_idx(*c1);
  int i2 = key_idx(*c2);
  float ea = gcn[(size_t)i1 * HID + t];
  float eb2 = gcn[(size_t)i2 * HID + t];
  float p0 = ea * eW[t * 3 + 0] + eb2 * eW[(128 + t) * 3 + 0];
  float p1 = ea * eW[t * 3 + 1] + eb2 * eW[(128 + t) * 3 + 1];
  float p2 = ea * eW[t * 3 + 2] + eb2 * eW[(128 + t) * 3 + 2];
  red[t] = p0; red[128 + t] = p1; red[256 + t] = p2;
  __syncthreads();
  for (int s = 64; s > 0; s >>= 1) {
    if (t < s) {
      red[t] += red[t + s];
      red[128 + t] += red[128 + t + s];
      red[256 + t] += red[256 + t + s];
    }
    __syncthreads();
  }
  if (t == 0) {
    float z0 = (red[0]   + ebias[0] + ge[0]) * INV_TAU;
    float z1 = (red[128] + ebias[1] + ge[1]) * INV_TAU;
    float z2 = (red[256] + ebias[2] + ge[2]) * INV_TAU;
    float m = fmaxf(z0, fmaxf(z1, z2));
    float e0 = expf(z0 - m), e1 = expf(z1 - m), e2 = expf(z2 - m);
    float inv = 1.f / (e0 + e1 + e2);
    out_base[0] = e0 * inv;
    out_base[1] = e1 * inv;
    out_base[2] = e2 * inv;
    out_base[3] = 1.0f;
  }
}

// ---------- launch ----------
extern "C" void kernel_launch(void* const* d_in, const int* in_sizes, int n_in,
                              void* d_out, int out_size, void* d_ws, size_t ws_size,
                              hipStream_t stream) {
  const float* x  = (const float*)d_in[0];
  const int* ei   = (const int*)d_in[1];
  const float* W1 = (const float*)d_in[2];
  const float* b1 = (const float*)d_in[3];
  const float* W2 = (const float*)d_in[4];
  const float* b2 = (const float*)d_in[5];
  const float* W3 = (const float*)d_in[6];
  const float* b3 = (const float*)d_in[7];
  const float* n1W = (const float*)d_in[8];
  const float* n1b = (const float*)d_in[9];
  const float* n2W = (const float*)d_in[10];
  const float* n2b = (const float*)d_in[11];
  const float* eW  = (const float*)d_in[12];
  const float* eb  = (const float*)d_in[13];
  const float* g1  = (const float*)d_in[16];
  const float* g2  = (const float*)d_in[17];
  const float* ge  = (const float*)d_in[18];

  int n    = in_sizes[0] / HID;
  int E    = in_sizes[1] / 2;
  int maxn = in_sizes[9];
  int nb   = (n + (1 << NB_SHIFT) - 1) >> NB_SHIFT;   // node buckets (<=256)
  float* out = (float*)d_out;

  char* ws = (char*)d_ws;
  size_t o = 0;
  ushort* H1B = (ushort*)(ws + o); o += (size_t)n * HID * 2;   // layer-1 out bf16
  ushort* H2B = (ushort*)(ws + o); o += (size_t)n * HID * 2;   // layer-2 out bf16
  ushort* HW  = (ushort*)(ws + o); o += (size_t)n * HID * 2;   // hW' bf16
  float* GCN  = (float*)(ws + o);  o += (size_t)n * HID * 4;   // layer-3 out fp32
  ushort* WT  = (ushort*)(ws + o); o += (size_t)3 * 128 * 128 * 2;
  float* EB1  = (float*)(ws + o);  o += (size_t)maxn * 4;
  float* EB2  = (float*)(ws + o);  o += (size_t)maxn * 4;
  int* ROWS   = (int*)(ws + o);    o += (size_t)n * 4;
  int* COL    = (int*)(ws + o);    o += (size_t)E * 4;
  int2* STAGED = (int2*)(ws + o);  o += (size_t)E * 8;
  float* DINV = (float*)(ws + o);  o += (size_t)n * 4;
  int* BSUMS  = (int*)(ws + o);    o += 1024 * 4;
  int* BCUR   = (int*)(ws + o);    o += 256 * 4;
  // ---- zeroed region ----
  char* zero_start = ws + o;
  int* CNT    = (int*)(ws + o);    o += (size_t)n * 4;
  int* CONN   = (int*)(ws + o);    o += (size_t)maxn * 4;
  float* PS   = (float*)(ws + o);  o += 128 * 4;
  float* PM   = (float*)(ws + o);  o += 128 * 4;
  unsigned long long* CELLS = (unsigned long long*)(ws + o);
  float* SUM1 = (float*)(ws + o + 16);
  float* SUM2 = (float*)(ws + o + 20);
  o += 64;
  size_t zero_bytes = (size_t)((ws + o) - zero_start);
  float* POOL = (float*)(ws + o);  o += 256 * 4;

  hipMemsetAsync(zero_start, 0, zero_bytes, stream);

  dim3 blk(256);
  int gE = (E + 255) / 256;
  int gN = (n + 255) / 256;
  int gHead = (maxn + 255) / 256;
  int gGemm = (n + 63) / 64;
  int gGather = (int)(((size_t)n * 32 + 255) / 256);
  int nScanBlocks = (n + 1023) / 1024;
  int gEB = (E + ECHUNK - 1) / ECHUNK;

  // weights -> bf16 transposed
  cvt_w<<<dim3(64, 3), blk, 0, stream>>>(W1, W2, W3, WT);

  // degrees + dinv + row offsets
  deg_hist<<<gE, blk, 0, stream>>>(ei, CNT, E);
  dinv_fin<<<gN, blk, 0, stream>>>(CNT, DINV, n);
  scan_block<<<nScanBlocks, blk, 0, stream>>>(CNT, ROWS, BSUMS, n);
  scan_tops<<<1, dim3(1024), 0, stream>>>(BSUMS, nScanBlocks);
  scan_add<<<gN, blk, 0, stream>>>(ROWS, BSUMS, n);

  // locality-preserving CSR build
  init_cursors<<<1, blk, 0, stream>>>(ROWS, BCUR, nb);
  edge_bucket<<<gEB, blk, 0, stream>>>(ei, E, nb, BCUR, STAGED);
  bucket_csr<<<nb, blk, 0, stream>>>(STAGED, ROWS, COL, E, n, nb);

  // layer 1: x (fp32, converted inline) -> H1B
  mfma_gemm<1><<<gGemm, blk, 0, stream>>>(x, WT, DINV, HW, n);
  gather_k<1><<<gGather, blk, 0, stream>>>(ROWS, CNT, COL, HW, DINV, b1, H1B, n);
  // layer 2: H1B -> H2B
  mfma_gemm<0><<<gGemm, blk, 0, stream>>>(H1B, WT + 128 * 128, DINV, HW, n);
  gather_k<1><<<gGather, blk, 0, stream>>>(ROWS, CNT, COL, HW, DINV, b2, H2B, n);
  // layer 3: H2B -> GCN (fp32)
  mfma_gemm<0><<<gGemm, blk, 0, stream>>>(H2B, WT + 2 * 128 * 128, DINV, HW, n);
  gather_k<0><<<gGather, blk, 0, stream>>>(ROWS, CNT, COL, HW, DINV, b3, GCN, n);

  // pool
  pool_kernel<<<(n + POOL_ROWS - 1) / POOL_ROWS, dim3(128), 0, stream>>>(GCN, PS, PM, n);
  pool_fin<<<1, dim3(128), 0, stream>>>(PS, PM, POOL, 1.0f / (float)n);

  // head 1 (exp+sum+argmax fused, no max-subtraction needed)
  head_fused<<<gHead, blk, 0, stream>>>(n1W, n1b, g1, POOL, nullptr, 0, EB1, &CELLS[0], SUM1, maxn, n);

  // conn mask from i1
  conn_kernel<<<gE, blk, 0, stream>>>(ei, E, &CELLS[0], CONN);

  // head 2
  head_fused<<<gHead, blk, 0, stream>>>(n2W, n2b, g2, POOL, CONN, 1, EB2, &CELLS[1], SUM2, maxn, n);

  // normalize both heads
  norm2<<<gHead, blk, 0, stream>>>(EB1, SUM1, EB2, SUM2, out, maxn);

  // edge + stop heads
  edge_head<<<1, dim3(128), 0, stream>>>(GCN, eW, eb, ge, &CELLS[0], &CELLS[1], out + 2 * (size_t)maxn);
}